// Round 1
// baseline (8535.838 us; speedup 1.0000x reference)
//
#include <hip/hip_runtime.h>
#include <hip/hip_bf16.h>

#define N_ 2
#define C_ 64
#define D_ 8
#define H_ 56
#define W_ 56
#define HW_ (H_*W_)        // 3136
#define P_ (D_*HW_)        // 25088
#define G_ 8
#define CPG_ 8
#define K_ 27
#define CO_OFF_ 648        // G * 3 * K

// ---------------------------------------------------------------------------
// Direct 3x3x3 conv, zero padding. out[n, co, p] = b[co] + sum_{ci,tap} w*x
// One thread per output element; co uniform per block -> scalar weight loads.
// ---------------------------------------------------------------------------
template<int CO>
__global__ __launch_bounds__(256) void conv3d_kernel(
    const float* __restrict__ x,    // [N, 64, P]
    const float* __restrict__ w,    // [CO, 64, 27]
    const float* __restrict__ b,    // [CO]
    float* __restrict__ out)        // [N, CO, P]
{
    int bid  = blockIdx.x;
    int pblk = bid % (P_/256);
    int co   = (bid / (P_/256)) % CO;
    int n    = bid / ((P_/256)*CO);
    int p  = pblk*256 + threadIdx.x;
    int d  = p / HW_;
    int hw = p % HW_;
    int h  = hw / W_;
    int wq = hw % W_;

    const float* wc0 = w + (size_t)co*C_*K_;
    const float* xb  = x + (size_t)n*C_*P_ + p;
    float acc = b[co];
    for (int ci = 0; ci < C_; ++ci) {
        const float* xc = xb + ci*P_;
        const float* wc = wc0 + ci*K_;
        #pragma unroll
        for (int kd = 0; kd < 3; ++kd) {
            bool vd = (unsigned)(d + kd - 1) < (unsigned)D_;
            #pragma unroll
            for (int kh = 0; kh < 3; ++kh) {
                bool vh = vd && ((unsigned)(h + kh - 1) < (unsigned)H_);
                int base = (kd-1)*HW_ + (kh-1)*W_;
                #pragma unroll
                for (int kw = 0; kw < 3; ++kw) {
                    bool v = vh && ((unsigned)(wq + kw - 1) < (unsigned)W_);
                    float xv = v ? xc[base + kw - 1] : 0.f;
                    acc = fmaf(wc[kd*9 + kh*3 + kw], xv, acc);
                }
            }
        }
    }
    out[((size_t)n*CO + co)*P_ + p] = acc;
}

// ---------------------------------------------------------------------------
// w1 [O=64, I=64, K=27] -> w1t [(i*27+k)][o]  (lane-coalesced for the GEMM)
// ---------------------------------------------------------------------------
__global__ void transpose_w1(const float* __restrict__ w1, float* __restrict__ w1t)
{
    int tid = blockIdx.x*256 + threadIdx.x;
    if (tid >= C_*C_*K_) return;
    int o  = tid / (C_*K_);
    int ik = tid % (C_*K_);
    w1t[ik*C_ + o] = w1[tid];
}

// ---------------------------------------------------------------------------
// Fused deformable conv: per block, TILE=8 contiguous w-positions.
// Phase 1: trilinear-gather vals[27][64][8] into LDS.
// Phase 2: out[o, t] = sum_{i,k} w1[o,i,k] * vals[k][i][t]  (LDS broadcast)
// ---------------------------------------------------------------------------
__global__ __launch_bounds__(256) void deform_kernel(
    const float* __restrict__ x,    // [N, 64, P]
    const float* __restrict__ off,  // [N, G, K, 3, P]
    const float* __restrict__ w1t,  // [1728, 64]
    float* __restrict__ out)        // [N, 64, P]
{
    __shared__ float vals[K_][C_][8];
    int bid = blockIdx.x;
    int n   = bid / (P_/8);
    int p0  = (bid % (P_/8))*8;       // 8 | HW_, 8 | W_: tile stays in one (d,h) row
    int d   = p0 / HW_;
    int hw  = p0 % HW_;
    int h   = hw / W_;
    int w0  = hw % W_;
    int tid = threadIdx.x;

    for (int task = tid; task < G_*K_*8; task += 256) {
        int t = task & 7;
        int g = (task >> 3) & 7;
        int k = task >> 6;
        int kd = k/9, kh = (k/3)%3, kw = k%3;
        size_t ob = ((((size_t)n*G_ + g)*K_ + k)*3)*P_ + p0 + t;
        float od = off[ob], oh = off[ob + P_], ow = off[ob + 2*(size_t)P_];
        float pd = (float)(d  + kd - 1) + od;
        float ph = (float)(h  + kh - 1) + oh;
        float pw = (float)(w0 + t + kw - 1) + ow;
        float fd0 = floorf(pd), fh0 = floorf(ph), fw0 = floorf(pw);
        int d0 = (int)fd0, h0 = (int)fh0, wi0 = (int)fw0;
        float fd = pd - fd0, fh = ph - fh0, fw = pw - fw0;
        const float* xg = x + ((size_t)n*C_ + g*CPG_)*P_;
        float res[CPG_];
        #pragma unroll
        for (int c = 0; c < CPG_; ++c) res[c] = 0.f;
        #pragma unroll
        for (int cd = 0; cd < 2; ++cd) {
            int id = d0 + cd;
            float wdt = cd ? fd : 1.f - fd;
            bool vdd = (unsigned)id < (unsigned)D_;
            int idc = min(max(id, 0), D_-1);
            #pragma unroll
            for (int ch = 0; ch < 2; ++ch) {
                int ih = h0 + ch;
                float wht = ch ? fh : 1.f - fh;
                bool vhh = (unsigned)ih < (unsigned)H_;
                int ihc = min(max(ih, 0), H_-1);
                #pragma unroll
                for (int cw = 0; cw < 2; ++cw) {
                    int iw = wi0 + cw;
                    float wwt = cw ? fw : 1.f - fw;
                    bool vww = (unsigned)iw < (unsigned)W_;
                    int iwc = min(max(iw, 0), W_-1);
                    float wgt = (vdd && vhh && vww) ? wdt*wht*wwt : 0.f;
                    int lin = (idc*H_ + ihc)*W_ + iwc;
                    #pragma unroll
                    for (int c = 0; c < CPG_; ++c)
                        res[c] = fmaf(wgt, xg[(size_t)c*P_ + lin], res[c]);
                }
            }
        }
        #pragma unroll
        for (int c = 0; c < CPG_; ++c)
            vals[k][g*CPG_ + c][t] = res[c];
    }
    __syncthreads();

    int o  = tid & 63;
    int ts = tid >> 6;   // 0..3 -> handles t=ts and t=ts+4
    float acc0 = 0.f, acc1 = 0.f;
    for (int i = 0; i < C_; ++i) {
        #pragma unroll
        for (int k = 0; k < K_; ++k) {
            float wv = w1t[(i*K_ + k)*C_ + o];   // coalesced, L1-hot
            acc0 = fmaf(wv, vals[k][i][ts],     acc0);  // LDS broadcast
            acc1 = fmaf(wv, vals[k][i][ts + 4], acc1);
        }
    }
    size_t outb = ((size_t)n*C_ + o)*P_ + p0;
    out[outb + ts]     = acc0;
    out[outb + ts + 4] = acc1;
}

// ---------------------------------------------------------------------------
// Per-channel batch stats: one block per channel. stats[c]=mean, stats[64+c]=rstd
// ---------------------------------------------------------------------------
__global__ __launch_bounds__(256) void bn_stats_kernel(
    const float* __restrict__ src, float* __restrict__ stats)
{
    int c   = blockIdx.x;
    int tid = threadIdx.x;
    float s = 0.f, q = 0.f;
    for (int n = 0; n < N_; ++n) {
        const float* p = src + ((size_t)n*C_ + c)*P_;
        for (int i = tid; i < P_; i += 256) {
            float v = p[i];
            s += v;
            q = fmaf(v, v, q);
        }
    }
    #pragma unroll
    for (int o = 32; o; o >>= 1) {
        s += __shfl_down(s, o);
        q += __shfl_down(q, o);
    }
    __shared__ float sh[2][4];
    int wave = tid >> 6;
    if ((tid & 63) == 0) { sh[0][wave] = s; sh[1][wave] = q; }
    __syncthreads();
    if (tid == 0) {
        float S = sh[0][0] + sh[0][1] + sh[0][2] + sh[0][3];
        float Q = sh[1][0] + sh[1][1] + sh[1][2] + sh[1][3];
        const float inv = 1.f / (float)(N_*P_);
        float m  = S * inv;
        float var = Q * inv - m*m;
        stats[c]      = m;
        stats[C_ + c] = rsqrtf(var + 1e-5f);
    }
}

// y = relu(gamma*(y-mean)*rstd + beta)   (in place)
__global__ __launch_bounds__(256) void bn_relu_kernel(
    float* __restrict__ y, const float* __restrict__ stats,
    const float* __restrict__ gamma, const float* __restrict__ beta)
{
    size_t idx = (size_t)blockIdx.x*256 + threadIdx.x;
    int c = (int)((idx / P_) % C_);
    float v = (y[idx] - stats[c]) * stats[C_ + c] * gamma[c] + beta[c];
    y[idx] = fmaxf(v, 0.f);
}

// out = relu(gamma*(y2-mean)*rstd + beta + x)
__global__ __launch_bounds__(256) void bn_add_relu_kernel(
    const float* __restrict__ y2, const float* __restrict__ x,
    const float* __restrict__ stats,
    const float* __restrict__ gamma, const float* __restrict__ beta,
    float* __restrict__ out)
{
    size_t idx = (size_t)blockIdx.x*256 + threadIdx.x;
    int c = (int)((idx / P_) % C_);
    float v = (y2[idx] - stats[c]) * stats[C_ + c] * gamma[c] + beta[c] + x[idx];
    out[idx] = fmaxf(v, 0.f);
}

// ---------------------------------------------------------------------------
extern "C" void kernel_launch(void* const* d_in, const int* in_sizes, int n_in,
                              void* d_out, int out_size, void* d_ws, size_t ws_size,
                              hipStream_t stream) {
    const float* x     = (const float*)d_in[0];
    const float* w_off = (const float*)d_in[1];
    const float* b_off = (const float*)d_in[2];
    const float* w1    = (const float*)d_in[3];
    const float* g1    = (const float*)d_in[4];
    const float* be1   = (const float*)d_in[5];
    const float* w2    = (const float*)d_in[6];
    const float* b2    = (const float*)d_in[7];
    const float* g2    = (const float*)d_in[8];
    const float* be2   = (const float*)d_in[9];
    float* out = (float*)d_out;

    float* ws   = (float*)d_ws;
    float* off  = ws;                               // N*648*P = 32,514,048 floats
    float* w1t  = off + (size_t)N_*CO_OFF_*P_;      // 110,592 floats
    float* y1   = w1t + (size_t)C_*C_*K_;           // N*64*P  = 3,211,264 floats
    float* y2   = y1  + (size_t)N_*C_*P_;           // N*64*P
    float* st1  = y2  + (size_t)N_*C_*P_;           // 128 floats
    float* st2  = st1 + 128;                        // 128 floats
    // total ~149 MB of ws

    conv3d_kernel<CO_OFF_><<<N_*CO_OFF_*(P_/256), 256, 0, stream>>>(x, w_off, b_off, off);
    transpose_w1<<<(C_*C_*K_ + 255)/256, 256, 0, stream>>>(w1, w1t);
    deform_kernel<<<N_*(P_/8), 256, 0, stream>>>(x, off, w1t, y1);
    bn_stats_kernel<<<C_, 256, 0, stream>>>(y1, st1);
    bn_relu_kernel<<<(N_*C_*P_)/256, 256, 0, stream>>>(y1, st1, g1, be1);
    conv3d_kernel<C_><<<N_*C_*(P_/256), 256, 0, stream>>>(y1, w2, b2, y2);
    bn_stats_kernel<<<C_, 256, 0, stream>>>(y2, st2);
    bn_add_relu_kernel<<<(N_*C_*P_)/256, 256, 0, stream>>>(y2, x, st2, g2, be2, out);
}

// Round 2
// 2343.674 us; speedup vs baseline: 3.6421x; 3.6421x over previous
//
#include <hip/hip_runtime.h>
#include <hip/hip_bf16.h>

#define N_ 2
#define C_ 64
#define D_ 8
#define H_ 56
#define W_ 56
#define HW_ (H_*W_)        // 3136
#define P_ (D_*HW_)        // 25088
#define PH_ (P_/2)         // 12544
#define G_ 8
#define CPG_ 8
#define K_ 27
#define CO_OFF_ 648        // G * 3 * K
#define MP_ 704            // conv_off M padded to 11*64
#define KK_ 1728           // C_ * K_  (GEMM K dim)
#define KB_ (KK_*2)        // bytes per bf16 row of A / Bt

typedef __attribute__((ext_vector_type(8))) short shortx8;
typedef __attribute__((ext_vector_type(4))) float floatx4;

__device__ inline float b2f(unsigned short u) {
    union { unsigned u; float f; } x; x.u = ((unsigned)u) << 16; return x.f;
}
__device__ inline unsigned short f2b(float f) {
    union { float f; unsigned u; } x; x.f = f;
    unsigned r = (x.u + 0x7fffu + ((x.u >> 16) & 1u)) >> 16;   // RNE
    return (unsigned short)r;
}

// ---------------------------------------------------------------------------
// fp32 -> bf16 cast (also used for w2 -> A2)
// ---------------------------------------------------------------------------
__global__ __launch_bounds__(256) void cast_f2b_kernel(
    const float* __restrict__ src, unsigned short* __restrict__ dst, int count)
{
    int i = blockIdx.x*256 + threadIdx.x;
    if (i < count) dst[i] = f2b(src[i]);
}

// w_off [648][1728] fp32 -> A1 [704][1728] bf16, zero rows >= 648
__global__ __launch_bounds__(256) void pad_w_kernel(
    const float* __restrict__ w, unsigned short* __restrict__ A)
{
    int i = blockIdx.x*256 + threadIdx.x;
    if (i >= MP_*KK_) return;
    int row = i / KK_;
    A[i] = (row < CO_OFF_) ? f2b(w[i]) : (unsigned short)0;
}

// w1 [O=64][I=64][K=27] fp32 -> w1t [(i*27+k)][o] fp32 (for deform phase 2)
__global__ void transpose_w1(const float* __restrict__ w1, float* __restrict__ w1t)
{
    int tid = blockIdx.x*256 + threadIdx.x;
    if (tid >= C_*C_*K_) return;
    int o  = tid / (C_*K_);
    int ik = tid % (C_*K_);
    w1t[ik*C_ + o] = w1[tid];
}

// ---------------------------------------------------------------------------
// p-major im2col: Bt[prow][ci*27+kk] = src[ci][p + delta(kk)] (bf16, 0-pad)
// One wave per p; 27 iters of 64 lanes covers the 1728 k-columns.
// ---------------------------------------------------------------------------
__global__ __launch_bounds__(256) void im2col_kernel(
    const unsigned short* __restrict__ src,   // [64][P_] bf16 (pre-offset by n)
    unsigned short* __restrict__ Bt,          // [PH_][1728] bf16
    int ph0)
{
    int wave = threadIdx.x >> 6, lane = threadIdx.x & 63;
    int prow = blockIdx.x*4 + wave;           // 0..PH_-1
    int p = ph0 + prow;
    int d = p / HW_, hw = p % HW_;
    int h = hw / W_, w = hw % W_;
    unsigned short* dst = Bt + (size_t)prow*KK_;
    #pragma unroll
    for (int i = 0; i < 27; ++i) {
        int idx = i*64 + lane;
        int ci = idx / 27, kk = idx % 27;
        int kd = kk/9 - 1;
        int r9 = kk % 9;
        int kh = r9/3 - 1, kw = r9%3 - 1;
        bool v = ((unsigned)(d+kd) < (unsigned)D_) &&
                 ((unsigned)(h+kh) < (unsigned)H_) &&
                 ((unsigned)(w+kw) < (unsigned)W_);
        unsigned short bits = 0;
        if (v) bits = src[(size_t)ci*P_ + p + kd*HW_ + kh*W_ + kw];
        dst[idx] = bits;
    }
}

// ---------------------------------------------------------------------------
// bf16 MFMA GEMM: out[co][col] = bias[co] + sum_k A[co][k]*Bt[p][k]
// Block tile 64(M) x 128(N), 4 waves, K=1728 in 54 steps of 32.
// global_load_lds(16B) stages A/B in MFMA fragment order -> conflict-free
// ds_read_b128 frag loads. C/D layout: col=lane&15, row=(lane>>4)*4+reg (m89).
// ---------------------------------------------------------------------------
__global__ __launch_bounds__(256) void gemm_kernel(
    const unsigned short* __restrict__ A,    // [Mpad][1728] bf16
    const unsigned short* __restrict__ Bt,   // [PH_][1728] bf16
    const float* __restrict__ bias,          // [Mvalid]
    unsigned short* __restrict__ out,        // bf16, out + co*P_ + col
    int Mvalid, int colbase)
{
    __shared__ __align__(16) short As[4*512];   // 4 chunks of 16m x 32k
    __shared__ __align__(16) short Bs[8*512];   // 8 chunks of 16n x 32k
    int w = threadIdx.x >> 6, lane = threadIdx.x & 63;
    int mtile = blockIdx.x / 98, ntile = blockIdx.x % 98;
    int m0 = mtile * 64, p0 = ntile * 128;
    int lm = lane & 15, lq = lane >> 4;

    // staging source addresses (fragment order: lane -> (row=lm, k8=lq))
    const char* Ab  = (const char*)A  + (size_t)(m0 + w*16 + lm)*KB_ + lq*16;
    const char* Bb0 = (const char*)Bt + (size_t)(p0 + w*32 + lm)*KB_ + lq*16;
    const char* Bb1 = Bb0 + (size_t)16*KB_;

    auto ldsA  = (__attribute__((address_space(3))) unsigned*)(As + w*512);
    auto ldsB0 = (__attribute__((address_space(3))) unsigned*)(Bs + (2*w)*512);
    auto ldsB1 = (__attribute__((address_space(3))) unsigned*)(Bs + (2*w+1)*512);

    floatx4 acc[4][2];
    #pragma unroll
    for (int i = 0; i < 4; ++i)
        #pragma unroll
        for (int j = 0; j < 2; ++j)
            acc[i][j] = (floatx4){0.f, 0.f, 0.f, 0.f};

    for (int kt = 0; kt < 54; ++kt) {
        __syncthreads();   // previous iter's frag reads done before overwrite
        __builtin_amdgcn_global_load_lds(
            (const __attribute__((address_space(1))) unsigned*)(Ab  + kt*64), ldsA,  16, 0, 0);
        __builtin_amdgcn_global_load_lds(
            (const __attribute__((address_space(1))) unsigned*)(Bb0 + kt*64), ldsB0, 16, 0, 0);
        __builtin_amdgcn_global_load_lds(
            (const __attribute__((address_space(1))) unsigned*)(Bb1 + kt*64), ldsB1, 16, 0, 0);
        __syncthreads();   // staging drained (vmcnt(0) before barrier)
        shortx8 b0 = *(const shortx8*)&Bs[(2*w)*512   + lane*8];
        shortx8 b1 = *(const shortx8*)&Bs[(2*w+1)*512 + lane*8];
        #pragma unroll
        for (int mt = 0; mt < 4; ++mt) {
            shortx8 a = *(const shortx8*)&As[mt*512 + lane*8];
            acc[mt][0] = __builtin_amdgcn_mfma_f32_16x16x32_bf16(a, b0, acc[mt][0], 0, 0, 0);
            acc[mt][1] = __builtin_amdgcn_mfma_f32_16x16x32_bf16(a, b1, acc[mt][1], 0, 0, 0);
        }
    }

    int colb = colbase + p0 + w*32 + lm;
    #pragma unroll
    for (int mt = 0; mt < 4; ++mt) {
        #pragma unroll
        for (int r = 0; r < 4; ++r) {
            int co = m0 + mt*16 + lq*4 + r;
            if (co < Mvalid) {
                float bv = bias[co];
                out[(size_t)co*P_ + colb]      = f2b(acc[mt][0][r] + bv);
                out[(size_t)co*P_ + colb + 16] = f2b(acc[mt][1][r] + bv);
            }
        }
    }
}

// ---------------------------------------------------------------------------
// Fused deformable conv (off now bf16, output bf16). Per block: 8 w-positions.
// ---------------------------------------------------------------------------
__global__ __launch_bounds__(256) void deform_kernel(
    const float* __restrict__ x,              // [N, 64, P] fp32
    const unsigned short* __restrict__ off,   // [N, G, K, 3, P] bf16
    const float* __restrict__ w1t,            // [1728, 64] fp32
    unsigned short* __restrict__ out)         // [N, 64, P] bf16
{
    __shared__ float vals[K_][C_][8];
    int bid = blockIdx.x;
    int n   = bid / (P_/8);
    int p0  = (bid % (P_/8))*8;
    int d   = p0 / HW_;
    int hw  = p0 % HW_;
    int h   = hw / W_;
    int w0  = hw % W_;
    int tid = threadIdx.x;

    for (int task = tid; task < G_*K_*8; task += 256) {
        int t = task & 7;
        int g = (task >> 3) & 7;
        int k = task >> 6;
        int kd = k/9, kh = (k/3)%3, kw = k%3;
        size_t ob = ((((size_t)n*G_ + g)*K_ + k)*3)*P_ + p0 + t;
        float od = b2f(off[ob]), oh = b2f(off[ob + P_]), ow = b2f(off[ob + 2*(size_t)P_]);
        float pd = (float)(d  + kd - 1) + od;
        float ph = (float)(h  + kh - 1) + oh;
        float pw = (float)(w0 + t + kw - 1) + ow;
        float fd0 = floorf(pd), fh0 = floorf(ph), fw0 = floorf(pw);
        int d0 = (int)fd0, h0 = (int)fh0, wi0 = (int)fw0;
        float fd = pd - fd0, fh = ph - fh0, fw = pw - fw0;
        const float* xg = x + ((size_t)n*C_ + g*CPG_)*P_;
        float res[CPG_];
        #pragma unroll
        for (int c = 0; c < CPG_; ++c) res[c] = 0.f;
        #pragma unroll
        for (int cd = 0; cd < 2; ++cd) {
            int id = d0 + cd;
            float wdt = cd ? fd : 1.f - fd;
            bool vdd = (unsigned)id < (unsigned)D_;
            int idc = min(max(id, 0), D_-1);
            #pragma unroll
            for (int ch = 0; ch < 2; ++ch) {
                int ih = h0 + ch;
                float wht = ch ? fh : 1.f - fh;
                bool vhh = (unsigned)ih < (unsigned)H_;
                int ihc = min(max(ih, 0), H_-1);
                #pragma unroll
                for (int cw = 0; cw < 2; ++cw) {
                    int iw = wi0 + cw;
                    float wwt = cw ? fw : 1.f - fw;
                    bool vww = (unsigned)iw < (unsigned)W_;
                    int iwc = min(max(iw, 0), W_-1);
                    float wgt = (vdd && vhh && vww) ? wdt*wht*wwt : 0.f;
                    int lin = (idc*H_ + ihc)*W_ + iwc;
                    #pragma unroll
                    for (int c = 0; c < CPG_; ++c)
                        res[c] = fmaf(wgt, xg[(size_t)c*P_ + lin], res[c]);
                }
            }
        }
        #pragma unroll
        for (int c = 0; c < CPG_; ++c)
            vals[k][g*CPG_ + c][t] = res[c];
    }
    __syncthreads();

    int o  = tid & 63;
    int ts = tid >> 6;
    float acc0 = 0.f, acc1 = 0.f;
    for (int i = 0; i < C_; ++i) {
        #pragma unroll
        for (int k = 0; k < K_; ++k) {
            float wv = w1t[(i*K_ + k)*C_ + o];
            acc0 = fmaf(wv, vals[k][i][ts],     acc0);
            acc1 = fmaf(wv, vals[k][i][ts + 4], acc1);
        }
    }
    size_t outb = ((size_t)n*C_ + o)*P_ + p0;
    out[outb + ts]     = f2b(acc0);
    out[outb + ts + 4] = f2b(acc1);
}

// ---------------------------------------------------------------------------
// BN stats over bf16 tensor: one block per channel
// ---------------------------------------------------------------------------
__global__ __launch_bounds__(256) void bn_stats_kernel(
    const unsigned short* __restrict__ src, float* __restrict__ stats)
{
    int c   = blockIdx.x;
    int tid = threadIdx.x;
    float s = 0.f, q = 0.f;
    for (int n = 0; n < N_; ++n) {
        const unsigned short* p = src + ((size_t)n*C_ + c)*P_;
        for (int i = tid; i < P_; i += 256) {
            float v = b2f(p[i]);
            s += v;
            q = fmaf(v, v, q);
        }
    }
    #pragma unroll
    for (int o = 32; o; o >>= 1) {
        s += __shfl_down(s, o);
        q += __shfl_down(q, o);
    }
    __shared__ float sh[2][4];
    int wave = tid >> 6;
    if ((tid & 63) == 0) { sh[0][wave] = s; sh[1][wave] = q; }
    __syncthreads();
    if (tid == 0) {
        float S = sh[0][0] + sh[0][1] + sh[0][2] + sh[0][3];
        float Q = sh[1][0] + sh[1][1] + sh[1][2] + sh[1][3];
        const float inv = 1.f / (float)(N_*P_);
        float m  = S * inv;
        float var = Q * inv - m*m;
        stats[c]      = m;
        stats[C_ + c] = rsqrtf(var + 1e-5f);
    }
}

// y = relu(gamma*(y-mean)*rstd + beta)   in place, bf16
__global__ __launch_bounds__(256) void bn_relu_kernel(
    unsigned short* __restrict__ y, const float* __restrict__ stats,
    const float* __restrict__ gamma, const float* __restrict__ beta)
{
    size_t idx = (size_t)blockIdx.x*256 + threadIdx.x;
    int c = (int)((idx / P_) % C_);
    float v = (b2f(y[idx]) - stats[c]) * stats[C_ + c] * gamma[c] + beta[c];
    y[idx] = f2b(fmaxf(v, 0.f));
}

// out = relu(gamma*(y2-mean)*rstd + beta + x)   fp32 out
__global__ __launch_bounds__(256) void bn_add_relu_kernel(
    const unsigned short* __restrict__ y2, const float* __restrict__ x,
    const float* __restrict__ stats,
    const float* __restrict__ gamma, const float* __restrict__ beta,
    float* __restrict__ out)
{
    size_t idx = (size_t)blockIdx.x*256 + threadIdx.x;
    int c = (int)((idx / P_) % C_);
    float v = (b2f(y2[idx]) - stats[c]) * stats[C_ + c] * gamma[c] + beta[c] + x[idx];
    out[idx] = fmaxf(v, 0.f);
}

// ---------------------------------------------------------------------------
extern "C" void kernel_launch(void* const* d_in, const int* in_sizes, int n_in,
                              void* d_out, int out_size, void* d_ws, size_t ws_size,
                              hipStream_t stream) {
    const float* x     = (const float*)d_in[0];
    const float* w_off = (const float*)d_in[1];
    const float* b_off = (const float*)d_in[2];
    const float* w1    = (const float*)d_in[3];
    const float* g1    = (const float*)d_in[4];
    const float* be1   = (const float*)d_in[5];
    const float* w2    = (const float*)d_in[6];
    const float* b2    = (const float*)d_in[7];
    const float* g2    = (const float*)d_in[8];
    const float* be2   = (const float*)d_in[9];
    float* out = (float*)d_out;

    // workspace layout (~132 MB)
    float* w1t = (float*)d_ws;                               // 110,592 f32
    float* st1 = w1t + (size_t)C_*C_*K_;                     // 128
    float* st2 = st1 + 128;                                  // 128
    unsigned short* Bt  = (unsigned short*)(st2 + 128);      // PH_*1728 bf16 (43.4 MB, reused)
    unsigned short* off = Bt  + (size_t)PH_*KK_;             // N*648*P bf16 (65 MB)
    unsigned short* xb  = off + (size_t)N_*CO_OFF_*P_;       // N*64*P bf16
    unsigned short* y1  = xb  + (size_t)N_*C_*P_;            // N*64*P bf16
    unsigned short* y2  = y1  + (size_t)N_*C_*P_;            // N*64*P bf16
    unsigned short* A1  = y2  + (size_t)N_*C_*P_;            // 704*1728 bf16
    unsigned short* A2  = A1  + (size_t)MP_*KK_;             // 64*1728 bf16

    // prep
    cast_f2b_kernel<<<(N_*C_*P_+255)/256, 256, 0, stream>>>(x, xb, N_*C_*P_);
    pad_w_kernel<<<(MP_*KK_+255)/256, 256, 0, stream>>>(w_off, A1);
    cast_f2b_kernel<<<(C_*KK_+255)/256, 256, 0, stream>>>(w2, A2, C_*KK_);
    transpose_w1<<<(C_*C_*K_+255)/256, 256, 0, stream>>>(w1, w1t);

    // conv_off: im2col + MFMA GEMM, per (n, half-P)
    for (int n = 0; n < N_; ++n)
        for (int hf = 0; hf < 2; ++hf) {
            im2col_kernel<<<PH_/4, 256, 0, stream>>>(xb + (size_t)n*C_*P_, Bt, hf*PH_);
            gemm_kernel<<<11*98, 256, 0, stream>>>(A1, Bt, b_off,
                off + (size_t)n*CO_OFF_*P_, CO_OFF_, hf*PH_);
        }

    // deformable conv -> y1 (bf16)
    deform_kernel<<<N_*(P_/8), 256, 0, stream>>>(x, off, w1t, y1);

    // BN1 + ReLU (in place on y1)
    bn_stats_kernel<<<C_, 256, 0, stream>>>(y1, st1);
    bn_relu_kernel<<<(N_*C_*P_)/256, 256, 0, stream>>>(y1, st1, g1, be1);

    // conv2: im2col + MFMA GEMM -> y2 (bf16)
    for (int n = 0; n < N_; ++n)
        for (int hf = 0; hf < 2; ++hf) {
            im2col_kernel<<<PH_/4, 256, 0, stream>>>(y1 + (size_t)n*C_*P_, Bt, hf*PH_);
            gemm_kernel<<<98, 256, 0, stream>>>(A2, Bt, b2,
                y2 + (size_t)n*C_*P_, C_, hf*PH_);
        }

    // BN2 + residual + ReLU -> out (fp32)
    bn_stats_kernel<<<C_, 256, 0, stream>>>(y2, st2);
    bn_add_relu_kernel<<<(N_*C_*P_)/256, 256, 0, stream>>>(y2, x, st2, g2, be2, out);
}

// Round 3
// 1463.460 us; speedup vs baseline: 5.8326x; 1.6015x over previous
//
#include <hip/hip_runtime.h>
#include <hip/hip_bf16.h>

#define N_ 2
#define C_ 64
#define D_ 8
#define H_ 56
#define W_ 56
#define HW_ (H_*W_)        // 3136
#define P_ (D_*HW_)        // 25088
#define PH_ (P_/2)         // 12544
#define G_ 8
#define CPG_ 8
#define K_ 27
#define CO_OFF_ 648        // G * 3 * K
#define MP_ 704            // conv_off M padded to 11*64
#define KK_ 1728           // GEMM K dim (= 64*27)
#define KB_ (KK_*2)        // bytes per bf16 row of A / Bt

typedef __attribute__((ext_vector_type(8))) short shortx8;
typedef __attribute__((ext_vector_type(4))) float floatx4;

__device__ inline float b2f(unsigned short u) {
    union { unsigned u; float f; } x; x.u = ((unsigned)u) << 16; return x.f;
}
__device__ inline unsigned short f2b(float f) {
    union { float f; unsigned u; } x; x.f = f;
    unsigned r = (x.u + 0x7fffu + ((x.u >> 16) & 1u)) >> 16;   // RNE
    return (unsigned short)r;
}
__device__ inline float lof(unsigned u) { union { unsigned u; float f; } x; x.u = u << 16; return x.f; }
__device__ inline float hif(unsigned u) { union { unsigned u; float f; } x; x.u = u & 0xffff0000u; return x.f; }

// ---------------------------------------------------------------------------
// fp32 -> bf16 cast
// ---------------------------------------------------------------------------
__global__ __launch_bounds__(256) void cast_f2b_kernel(
    const float* __restrict__ src, unsigned short* __restrict__ dst, int count)
{
    int i = blockIdx.x*256 + threadIdx.x;
    if (i < count) dst[i] = f2b(src[i]);
}

// w_off [648][1728] fp32 -> A1 [704][1728] bf16, zero rows >= 648
__global__ __launch_bounds__(256) void pad_w_kernel(
    const float* __restrict__ w, unsigned short* __restrict__ A)
{
    int i = blockIdx.x*256 + threadIdx.x;
    if (i >= MP_*KK_) return;
    int row = i / KK_;
    A[i] = (row < CO_OFF_) ? f2b(w[i]) : (unsigned short)0;
}

// w1 [O=64][I=64][Ktap=27] fp32 -> A1t[o][k*64+i] bf16 (k-major K-order)
__global__ __launch_bounds__(256) void perm_w1_kernel(
    const float* __restrict__ w1, unsigned short* __restrict__ A1t)
{
    int tid = blockIdx.x*256 + threadIdx.x;
    if (tid >= C_*KK_) return;
    int o  = tid / KK_;
    int r  = tid % KK_;
    int k  = r / 64, i = r % 64;
    A1t[tid] = f2b(w1[((size_t)o*C_ + i)*K_ + k]);
}

// xb [N][64][P] bf16 -> xt [N][P][64] bf16  (64p x 64c LDS tile transpose)
__global__ __launch_bounds__(256) void transpose_xt_kernel(
    const unsigned short* __restrict__ xb, unsigned short* __restrict__ xt)
{
    __shared__ unsigned short tile[64][65];
    int b  = blockIdx.x;
    int n  = b / (P_/64);
    int p0 = (b % (P_/64))*64;
    int tid = threadIdx.x;
    int j  = tid & 63;
    int c0 = (tid >> 6)*16;
    for (int r = 0; r < 16; ++r)
        tile[c0 + r][j] = xb[((size_t)n*C_ + c0 + r)*P_ + p0 + j];
    __syncthreads();
    unsigned* dst = (unsigned*)(xt + ((size_t)n*P_ + p0)*C_);
    #pragma unroll
    for (int it = 0; it < 8; ++it) {
        int wi  = it*256 + tid;
        int row = wi >> 5;
        int c   = (wi & 31)*2;
        unsigned lo = tile[c][row], hi = tile[c+1][row];
        dst[(size_t)row*32 + (wi & 31)] = lo | (hi << 16);
    }
}

// ---------------------------------------------------------------------------
// p-major im2col for conv_off: Bt[prow][ci*27+kk]
// ---------------------------------------------------------------------------
__global__ __launch_bounds__(256) void im2col_kernel(
    const unsigned short* __restrict__ src,   // [64][P_] bf16 (pre-offset by n)
    unsigned short* __restrict__ Bt,          // [PH_][1728] bf16
    int ph0)
{
    int wave = threadIdx.x >> 6, lane = threadIdx.x & 63;
    int prow = blockIdx.x*4 + wave;
    int p = ph0 + prow;
    int d = p / HW_, hw = p % HW_;
    int h = hw / W_, w = hw % W_;
    unsigned short* dst = Bt + (size_t)prow*KK_;
    #pragma unroll
    for (int i = 0; i < 27; ++i) {
        int idx = i*64 + lane;
        int ci = idx / 27, kk = idx % 27;
        int kd = kk/9 - 1;
        int r9 = kk % 9;
        int kh = r9/3 - 1, kw = r9%3 - 1;
        bool v = ((unsigned)(d+kd) < (unsigned)D_) &&
                 ((unsigned)(h+kh) < (unsigned)H_) &&
                 ((unsigned)(w+kw) < (unsigned)W_);
        unsigned short bits = 0;
        if (v) bits = src[(size_t)ci*P_ + p + kd*HW_ + kh*W_ + kw];
        dst[idx] = bits;
    }
}

// im2col for conv2 with fused BN1+ReLU on the read (zero-padding stays 0)
__global__ __launch_bounds__(256) void im2col_bn_kernel(
    const unsigned short* __restrict__ src,   // y1 raw [64][P_] bf16
    const float* __restrict__ stats,          // [64] mean, [64] rstd
    const float* __restrict__ gamma, const float* __restrict__ beta,
    unsigned short* __restrict__ Bt, int ph0)
{
    int wave = threadIdx.x >> 6, lane = threadIdx.x & 63;
    int prow = blockIdx.x*4 + wave;
    int p = ph0 + prow;
    int d = p / HW_, hw = p % HW_;
    int h = hw / W_, w = hw % W_;
    unsigned short* dst = Bt + (size_t)prow*KK_;
    #pragma unroll
    for (int i = 0; i < 27; ++i) {
        int idx = i*64 + lane;
        int ci = idx / 27, kk = idx % 27;
        int kd = kk/9 - 1;
        int r9 = kk % 9;
        int kh = r9/3 - 1, kw = r9%3 - 1;
        bool v = ((unsigned)(d+kd) < (unsigned)D_) &&
                 ((unsigned)(h+kh) < (unsigned)H_) &&
                 ((unsigned)(w+kw) < (unsigned)W_);
        unsigned short bits = 0;
        if (v) {
            float val = b2f(src[(size_t)ci*P_ + p + kd*HW_ + kh*W_ + kw]);
            val = fmaxf((val - stats[ci])*stats[C_+ci]*gamma[ci] + beta[ci], 0.f);
            bits = f2b(val);
        }
        dst[idx] = bits;
    }
}

// ---------------------------------------------------------------------------
// Deform gather: Bt[prow][k*64 + g*8 + c] = trilinear(xt, p + tap_k + off)
// One thread per (g,k,p): 3 coalesced bf16 offset loads, 8x 16B corner loads
// (all 8 channels of the group in one load), one 16B store. No LDS.
// ---------------------------------------------------------------------------
__global__ __launch_bounds__(256) void gather_kernel(
    const unsigned short* __restrict__ xt,   // [N][P][64] bf16
    const unsigned short* __restrict__ off,  // [N][G][K][3][P] bf16
    unsigned short* __restrict__ Bt,         // [PH_][1728] bf16 (k-major)
    int n, int ph0)
{
    int bid  = blockIdx.x;
    int pblk = bid % (PH_/256);
    int gk   = bid / (PH_/256);      // 0..215
    int g = gk % 8, k = gk / 8;
    int row = pblk*256 + threadIdx.x;
    int p = ph0 + row;
    int d = p / HW_, hw = p % HW_;
    int h = hw / W_, w = hw % W_;
    int kd = k/9 - 1, kh = (k/3)%3 - 1, kw = k%3 - 1;

    size_t ob = ((((size_t)n*G_ + g)*K_ + k)*3)*P_ + p;
    float od = b2f(off[ob]);
    float oh = b2f(off[ob + P_]);
    float ow = b2f(off[ob + 2*(size_t)P_]);
    float pd = (float)(d + kd) + od;
    float ph = (float)(h + kh) + oh;
    float pw = (float)(w + kw) + ow;
    float fd0 = floorf(pd), fh0 = floorf(ph), fw0 = floorf(pw);
    int d0 = (int)fd0, h0 = (int)fh0, w0i = (int)fw0;
    float fd = pd - fd0, fh = ph - fh0, fw = pw - fw0;

    const uint4* xg = (const uint4*)(xt + ((size_t)n*P_)*C_ + g*CPG_);
    float res[CPG_];
    #pragma unroll
    for (int c = 0; c < CPG_; ++c) res[c] = 0.f;
    #pragma unroll
    for (int cd = 0; cd < 2; ++cd) {
        int id = d0 + cd;
        float wdt = cd ? fd : 1.f - fd;
        bool vdd = (unsigned)id < (unsigned)D_;
        int idc = min(max(id, 0), D_-1);
        #pragma unroll
        for (int ch = 0; ch < 2; ++ch) {
            int ih = h0 + ch;
            float wht = ch ? fh : 1.f - fh;
            bool vhh = (unsigned)ih < (unsigned)H_;
            int ihc = min(max(ih, 0), H_-1);
            #pragma unroll
            for (int cw = 0; cw < 2; ++cw) {
                int iw = w0i + cw;
                float wwt = cw ? fw : 1.f - fw;
                bool vww = (unsigned)iw < (unsigned)W_;
                int iwc = min(max(iw, 0), W_-1);
                float wgt = (vdd && vhh && vww) ? wdt*wht*wwt : 0.f;
                int lin = (idc*H_ + ihc)*W_ + iwc;
                uint4 v4 = xg[(size_t)lin*(C_/8)];   // 16B = 8 bf16 channels
                res[0] = fmaf(wgt, lof(v4.x), res[0]);
                res[1] = fmaf(wgt, hif(v4.x), res[1]);
                res[2] = fmaf(wgt, lof(v4.y), res[2]);
                res[3] = fmaf(wgt, hif(v4.y), res[3]);
                res[4] = fmaf(wgt, lof(v4.z), res[4]);
                res[5] = fmaf(wgt, hif(v4.z), res[5]);
                res[6] = fmaf(wgt, lof(v4.w), res[6]);
                res[7] = fmaf(wgt, hif(v4.w), res[7]);
            }
        }
    }
    uint4 o4;
    o4.x = (unsigned)f2b(res[0]) | ((unsigned)f2b(res[1]) << 16);
    o4.y = (unsigned)f2b(res[2]) | ((unsigned)f2b(res[3]) << 16);
    o4.z = (unsigned)f2b(res[4]) | ((unsigned)f2b(res[5]) << 16);
    o4.w = (unsigned)f2b(res[6]) | ((unsigned)f2b(res[7]) << 16);
    *(uint4*)(Bt + (size_t)row*KK_ + k*64 + g*CPG_) = o4;
}

// ---------------------------------------------------------------------------
// bf16 MFMA GEMM: out[co][col] = bias[co] + sum_k A[co][k]*Bt[p][k]
// Block tile 64(M) x 128(N), 4 waves, K=1728 in 54 steps of 32.
// ---------------------------------------------------------------------------
__global__ __launch_bounds__(256) void gemm_kernel(
    const unsigned short* __restrict__ A,    // [Mpad][1728] bf16
    const unsigned short* __restrict__ Bt,   // [PH_][1728] bf16
    const float* __restrict__ bias,          // [Mvalid] or nullptr
    unsigned short* __restrict__ out,        // bf16, out + co*P_ + col
    int Mvalid, int colbase)
{
    __shared__ __align__(16) short As[4*512];
    __shared__ __align__(16) short Bs[8*512];
    int w = threadIdx.x >> 6, lane = threadIdx.x & 63;
    int mtile = blockIdx.x / 98, ntile = blockIdx.x % 98;
    int m0 = mtile * 64, p0 = ntile * 128;
    int lm = lane & 15, lq = lane >> 4;

    const char* Ab  = (const char*)A  + (size_t)(m0 + w*16 + lm)*KB_ + lq*16;
    const char* Bb0 = (const char*)Bt + (size_t)(p0 + w*32 + lm)*KB_ + lq*16;
    const char* Bb1 = Bb0 + (size_t)16*KB_;

    auto ldsA  = (__attribute__((address_space(3))) unsigned*)(As + w*512);
    auto ldsB0 = (__attribute__((address_space(3))) unsigned*)(Bs + (2*w)*512);
    auto ldsB1 = (__attribute__((address_space(3))) unsigned*)(Bs + (2*w+1)*512);

    floatx4 acc[4][2];
    #pragma unroll
    for (int i = 0; i < 4; ++i)
        #pragma unroll
        for (int j = 0; j < 2; ++j)
            acc[i][j] = (floatx4){0.f, 0.f, 0.f, 0.f};

    for (int kt = 0; kt < 54; ++kt) {
        __syncthreads();
        __builtin_amdgcn_global_load_lds(
            (const __attribute__((address_space(1))) unsigned*)(Ab  + kt*64), ldsA,  16, 0, 0);
        __builtin_amdgcn_global_load_lds(
            (const __attribute__((address_space(1))) unsigned*)(Bb0 + kt*64), ldsB0, 16, 0, 0);
        __builtin_amdgcn_global_load_lds(
            (const __attribute__((address_space(1))) unsigned*)(Bb1 + kt*64), ldsB1, 16, 0, 0);
        __syncthreads();
        shortx8 b0 = *(const shortx8*)&Bs[(2*w)*512   + lane*8];
        shortx8 b1 = *(const shortx8*)&Bs[(2*w+1)*512 + lane*8];
        #pragma unroll
        for (int mt = 0; mt < 4; ++mt) {
            shortx8 a = *(const shortx8*)&As[mt*512 + lane*8];
            acc[mt][0] = __builtin_amdgcn_mfma_f32_16x16x32_bf16(a, b0, acc[mt][0], 0, 0, 0);
            acc[mt][1] = __builtin_amdgcn_mfma_f32_16x16x32_bf16(a, b1, acc[mt][1], 0, 0, 0);
        }
    }

    int colb = colbase + p0 + w*32 + lm;
    #pragma unroll
    for (int mt = 0; mt < 4; ++mt) {
        #pragma unroll
        for (int r = 0; r < 4; ++r) {
            int co = m0 + mt*16 + lq*4 + r;
            if (co < Mvalid) {
                float bv = bias ? bias[co] : 0.f;
                out[(size_t)co*P_ + colb]      = f2b(acc[mt][0][r] + bv);
                out[(size_t)co*P_ + colb + 16] = f2b(acc[mt][1][r] + bv);
            }
        }
    }
}

// ---------------------------------------------------------------------------
// BN stats over bf16 tensor: one block per channel
// ---------------------------------------------------------------------------
__global__ __launch_bounds__(256) void bn_stats_kernel(
    const unsigned short* __restrict__ src, float* __restrict__ stats)
{
    int c   = blockIdx.x;
    int tid = threadIdx.x;
    float s = 0.f, q = 0.f;
    for (int n = 0; n < N_; ++n) {
        const unsigned short* p = src + ((size_t)n*C_ + c)*P_;
        for (int i = tid; i < P_; i += 256) {
            float v = b2f(p[i]);
            s += v;
            q = fmaf(v, v, q);
        }
    }
    #pragma unroll
    for (int o = 32; o; o >>= 1) {
        s += __shfl_down(s, o);
        q += __shfl_down(q, o);
    }
    __shared__ float sh[2][4];
    int wave = tid >> 6;
    if ((tid & 63) == 0) { sh[0][wave] = s; sh[1][wave] = q; }
    __syncthreads();
    if (tid == 0) {
        float S = sh[0][0] + sh[0][1] + sh[0][2] + sh[0][3];
        float Q = sh[1][0] + sh[1][1] + sh[1][2] + sh[1][3];
        const float inv = 1.f / (float)(N_*P_);
        float m  = S * inv;
        float var = Q * inv - m*m;
        stats[c]      = m;
        stats[C_ + c] = rsqrtf(var + 1e-5f);
    }
}

// out = relu(gamma*(y2-mean)*rstd + beta + x)   fp32 out
__global__ __launch_bounds__(256) void bn_add_relu_kernel(
    const unsigned short* __restrict__ y2, const float* __restrict__ x,
    const float* __restrict__ stats,
    const float* __restrict__ gamma, const float* __restrict__ beta,
    float* __restrict__ out)
{
    size_t idx = (size_t)blockIdx.x*256 + threadIdx.x;
    int c = (int)((idx / P_) % C_);
    float v = (b2f(y2[idx]) - stats[c]) * stats[C_ + c] * gamma[c] + beta[c] + x[idx];
    out[idx] = fmaxf(v, 0.f);
}

// ---------------------------------------------------------------------------
extern "C" void kernel_launch(void* const* d_in, const int* in_sizes, int n_in,
                              void* d_out, int out_size, void* d_ws, size_t ws_size,
                              hipStream_t stream) {
    const float* x     = (const float*)d_in[0];
    const float* w_off = (const float*)d_in[1];
    const float* b_off = (const float*)d_in[2];
    const float* w1    = (const float*)d_in[3];
    const float* g1    = (const float*)d_in[4];
    const float* be1   = (const float*)d_in[5];
    const float* w2    = (const float*)d_in[6];
    const float* b2    = (const float*)d_in[7];
    const float* g2    = (const float*)d_in[8];
    const float* be2   = (const float*)d_in[9];
    float* out = (float*)d_out;

    // workspace (~137 MB)
    float* st1 = (float*)d_ws;                               // 128
    float* st2 = st1 + 128;                                  // 128
    unsigned short* Bt  = (unsigned short*)(st2 + 128);      // PH_*1728 (43.4 MB, reused)
    unsigned short* off = Bt  + (size_t)PH_*KK_;             // N*648*P bf16 (65 MB)
    unsigned short* xb  = off + (size_t)N_*CO_OFF_*P_;       // N*64*P bf16
    unsigned short* xt  = xb  + (size_t)N_*C_*P_;            // N*P*64 bf16
    unsigned short* y1  = xt  + (size_t)N_*C_*P_;            // N*64*P bf16
    unsigned short* y2  = y1  + (size_t)N_*C_*P_;            // N*64*P bf16
    unsigned short* A1  = y2  + (size_t)N_*C_*P_;            // 704*1728 bf16
    unsigned short* A2  = A1  + (size_t)MP_*KK_;             // 64*1728 bf16
    unsigned short* A1t = A2  + (size_t)C_*KK_;              // 64*1728 bf16

    // prep
    cast_f2b_kernel<<<(N_*C_*P_+255)/256, 256, 0, stream>>>(x, xb, N_*C_*P_);
    transpose_xt_kernel<<<N_*(P_/64), 256, 0, stream>>>(xb, xt);
    pad_w_kernel<<<(MP_*KK_+255)/256, 256, 0, stream>>>(w_off, A1);
    cast_f2b_kernel<<<(C_*KK_+255)/256, 256, 0, stream>>>(w2, A2, C_*KK_);
    perm_w1_kernel<<<(C_*KK_+255)/256, 256, 0, stream>>>(w1, A1t);

    // conv_off: im2col + MFMA GEMM, per (n, half-P)
    for (int n = 0; n < N_; ++n)
        for (int hf = 0; hf < 2; ++hf) {
            im2col_kernel<<<PH_/4, 256, 0, stream>>>(xb + (size_t)n*C_*P_, Bt, hf*PH_);
            gemm_kernel<<<11*98, 256, 0, stream>>>(A1, Bt, b_off,
                off + (size_t)n*CO_OFF_*P_, CO_OFF_, hf*PH_);
        }

    // deformable conv: gather (deformed im2col) + MFMA GEMM -> y1 raw bf16
    for (int n = 0; n < N_; ++n)
        for (int hf = 0; hf < 2; ++hf) {
            gather_kernel<<<216*(PH_/256), 256, 0, stream>>>(xt, off, Bt, n, hf*PH_);
            gemm_kernel<<<98, 256, 0, stream>>>(A1t, Bt, (const float*)nullptr,
                y1 + (size_t)n*C_*P_, C_, hf*PH_);
        }

    // BN1 stats (apply fused into conv2's im2col)
    bn_stats_kernel<<<C_, 256, 0, stream>>>(y1, st1);

    // conv2: im2col(+BN1+ReLU) + MFMA GEMM -> y2 bf16
    for (int n = 0; n < N_; ++n)
        for (int hf = 0; hf < 2; ++hf) {
            im2col_bn_kernel<<<PH_/4, 256, 0, stream>>>(y1 + (size_t)n*C_*P_,
                st1, g1, be1, Bt, hf*PH_);
            gemm_kernel<<<98, 256, 0, stream>>>(A2, Bt, b2,
                y2 + (size_t)n*C_*P_, C_, hf*PH_);
        }

    // BN2 + residual + ReLU -> out (fp32)
    bn_stats_kernel<<<C_, 256, 0, stream>>>(y2, st2);
    bn_add_relu_kernel<<<(N_*C_*P_)/256, 256, 0, stream>>>(y2, x, st2, g2, be2, out);
}

// Round 4
// 1156.277 us; speedup vs baseline: 7.3822x; 1.2657x over previous
//
#include <hip/hip_runtime.h>
#include <hip/hip_bf16.h>

#define N_ 2
#define C_ 64
#define D_ 8
#define H_ 56
#define W_ 56
#define HW_ (H_*W_)        // 3136
#define P_ (D_*HW_)        // 25088
#define G_ 8
#define CPG_ 8
#define K_ 27
#define CO_OFF_ 648        // G * 3 * K
#define MP_ 768            // conv_off M padded to 6*128
#define KK_ 1728           // GEMM K dim (= 64*27)
#define KB_ (KK_*2)        // bytes per bf16 row of A / Bt

typedef __attribute__((ext_vector_type(8))) short shortx8;
typedef __attribute__((ext_vector_type(4))) float floatx4;
#define AS1 __attribute__((address_space(1)))
#define AS3 __attribute__((address_space(3)))

__device__ inline float b2f(unsigned short u) {
    union { unsigned u; float f; } x; x.u = ((unsigned)u) << 16; return x.f;
}
__device__ inline unsigned short f2b(float f) {
    union { float f; unsigned u; } x; x.f = f;
    unsigned r = (x.u + 0x7fffu + ((x.u >> 16) & 1u)) >> 16;   // RNE
    return (unsigned short)r;
}
__device__ inline float lof(unsigned u) { union { unsigned u; float f; } x; x.u = u << 16; return x.f; }
__device__ inline float hif(unsigned u) { union { unsigned u; float f; } x; x.u = u & 0xffff0000u; return x.f; }

// ---------------------------------------------------------------------------
__global__ __launch_bounds__(256) void cast_f2b_kernel(
    const float* __restrict__ src, unsigned short* __restrict__ dst, int count)
{
    int i = blockIdx.x*256 + threadIdx.x;
    if (i < count) dst[i] = f2b(src[i]);
}

// w_off [648][1728] fp32 -> A1 [768][1728] bf16, zero rows >= 648
__global__ __launch_bounds__(256) void pad_w_kernel(
    const float* __restrict__ w, unsigned short* __restrict__ A)
{
    int i = blockIdx.x*256 + threadIdx.x;
    if (i >= MP_*KK_) return;
    int row = i / KK_;
    A[i] = (row < CO_OFF_) ? f2b(w[i]) : (unsigned short)0;
}

// w1 [O=64][I=64][Ktap=27] fp32 -> A1t[o][k*64+i] bf16 (k-major K-order)
__global__ __launch_bounds__(256) void perm_w1_kernel(
    const float* __restrict__ w1, unsigned short* __restrict__ A1t)
{
    int tid = blockIdx.x*256 + threadIdx.x;
    if (tid >= C_*KK_) return;
    int o  = tid / KK_;
    int r  = tid % KK_;
    int k  = r / 64, i = r % 64;
    A1t[tid] = f2b(w1[((size_t)o*C_ + i)*K_ + k]);
}

// xb [N][64][P] bf16 -> xt [N][P][64] bf16  (64p x 64c LDS tile transpose)
__global__ __launch_bounds__(256) void transpose_xt_kernel(
    const unsigned short* __restrict__ xb, unsigned short* __restrict__ xt)
{
    __shared__ unsigned short tile[64][65];
    int b  = blockIdx.x;
    int n  = b / (P_/64);
    int p0 = (b % (P_/64))*64;
    int tid = threadIdx.x;
    int j  = tid & 63;
    int c0 = (tid >> 6)*16;
    for (int r = 0; r < 16; ++r)
        tile[c0 + r][j] = xb[((size_t)n*C_ + c0 + r)*P_ + p0 + j];
    __syncthreads();
    unsigned* dst = (unsigned*)(xt + ((size_t)n*P_ + p0)*C_);
    #pragma unroll
    for (int it = 0; it < 8; ++it) {
        int wi  = it*256 + tid;
        int row = wi >> 5;
        int c   = (wi & 31)*2;
        unsigned lo = tile[c][row], hi = tile[c+1][row];
        dst[(size_t)row*32 + (wi & 31)] = lo | (hi << 16);
    }
}

// ---------------------------------------------------------------------------
// p-major im2col for conv_off: Bt[p][ci*27+kk], full P
// ---------------------------------------------------------------------------
__global__ __launch_bounds__(256) void im2col_kernel(
    const unsigned short* __restrict__ src,   // [64][P_] bf16 (pre-offset by n)
    unsigned short* __restrict__ Bt)          // [P_][1728] bf16
{
    int wave = threadIdx.x >> 6, lane = threadIdx.x & 63;
    int p = blockIdx.x*4 + wave;
    int d = p / HW_, hw = p % HW_;
    int h = hw / W_, w = hw % W_;
    unsigned short* dst = Bt + (size_t)p*KK_;
    #pragma unroll
    for (int i = 0; i < 27; ++i) {
        int idx = i*64 + lane;
        int ci = idx / 27, kk = idx % 27;
        int kd = kk/9 - 1;
        int r9 = kk % 9;
        int kh = r9/3 - 1, kw = r9%3 - 1;
        bool v = ((unsigned)(d+kd) < (unsigned)D_) &&
                 ((unsigned)(h+kh) < (unsigned)H_) &&
                 ((unsigned)(w+kw) < (unsigned)W_);
        unsigned short bits = 0;
        if (v) bits = src[(size_t)ci*P_ + p + kd*HW_ + kh*W_ + kw];
        dst[idx] = bits;
    }
}

// im2col for conv2 with fused BN1+ReLU on the read
__global__ __launch_bounds__(256) void im2col_bn_kernel(
    const unsigned short* __restrict__ src,   // y1 raw [64][P_] bf16
    const float* __restrict__ stats,
    const float* __restrict__ gamma, const float* __restrict__ beta,
    unsigned short* __restrict__ Bt)
{
    int wave = threadIdx.x >> 6, lane = threadIdx.x & 63;
    int p = blockIdx.x*4 + wave;
    int d = p / HW_, hw = p % HW_;
    int h = hw / W_, w = hw % W_;
    unsigned short* dst = Bt + (size_t)p*KK_;
    #pragma unroll
    for (int i = 0; i < 27; ++i) {
        int idx = i*64 + lane;
        int ci = idx / 27, kk = idx % 27;
        int kd = kk/9 - 1;
        int r9 = kk % 9;
        int kh = r9/3 - 1, kw = r9%3 - 1;
        bool v = ((unsigned)(d+kd) < (unsigned)D_) &&
                 ((unsigned)(h+kh) < (unsigned)H_) &&
                 ((unsigned)(w+kw) < (unsigned)W_);
        unsigned short bits = 0;
        if (v) {
            float val = b2f(src[(size_t)ci*P_ + p + kd*HW_ + kh*W_ + kw]);
            val = fmaxf((val - stats[ci])*stats[C_+ci]*gamma[ci] + beta[ci], 0.f);
            bits = f2b(val);
        }
        dst[idx] = bits;
    }
}

// ---------------------------------------------------------------------------
// Deform gather: Bt[p][k*64 + g*8 + c] = trilinear(xt, p + tap_k + off)
// ---------------------------------------------------------------------------
__global__ __launch_bounds__(256) void gather_kernel(
    const unsigned short* __restrict__ xt,   // [N][P][64] bf16
    const unsigned short* __restrict__ off,  // [G][K][3][P] bf16 (per-n)
    unsigned short* __restrict__ Bt,         // [P_][1728] bf16 (k-major)
    int n)
{
    int bid  = blockIdx.x;
    int pblk = bid % (P_/256);
    int gk   = bid / (P_/256);      // 0..215
    int g = gk % 8, k = gk / 8;
    int p = pblk*256 + threadIdx.x;
    int d = p / HW_, hw = p % HW_;
    int h = hw / W_, w = hw % W_;
    int kd = k/9 - 1, kh = (k/3)%3 - 1, kw = k%3 - 1;

    size_t ob = (((size_t)g*K_ + k)*3)*P_ + p;
    float od = b2f(off[ob]);
    float oh = b2f(off[ob + P_]);
    float ow = b2f(off[ob + 2*(size_t)P_]);
    float pd = (float)(d + kd) + od;
    float ph = (float)(h + kh) + oh;
    float pw = (float)(w + kw) + ow;
    float fd0 = floorf(pd), fh0 = floorf(ph), fw0 = floorf(pw);
    int d0 = (int)fd0, h0 = (int)fh0, w0i = (int)fw0;
    float fd = pd - fd0, fh = ph - fh0, fw = pw - fw0;

    const uint4* xg = (const uint4*)(xt + ((size_t)n*P_)*C_ + g*CPG_);
    float res[CPG_];
    #pragma unroll
    for (int c = 0; c < CPG_; ++c) res[c] = 0.f;
    #pragma unroll
    for (int cd = 0; cd < 2; ++cd) {
        int id = d0 + cd;
        float wdt = cd ? fd : 1.f - fd;
        bool vdd = (unsigned)id < (unsigned)D_;
        int idc = min(max(id, 0), D_-1);
        #pragma unroll
        for (int ch = 0; ch < 2; ++ch) {
            int ih = h0 + ch;
            float wht = ch ? fh : 1.f - fh;
            bool vhh = (unsigned)ih < (unsigned)H_;
            int ihc = min(max(ih, 0), H_-1);
            #pragma unroll
            for (int cw = 0; cw < 2; ++cw) {
                int iw = w0i + cw;
                float wwt = cw ? fw : 1.f - fw;
                bool vww = (unsigned)iw < (unsigned)W_;
                int iwc = min(max(iw, 0), W_-1);
                float wgt = (vdd && vhh && vww) ? wdt*wht*wwt : 0.f;
                int lin = (idc*H_ + ihc)*W_ + iwc;
                uint4 v4 = xg[(size_t)lin*(C_/8)];
                res[0] = fmaf(wgt, lof(v4.x), res[0]);
                res[1] = fmaf(wgt, hif(v4.x), res[1]);
                res[2] = fmaf(wgt, lof(v4.y), res[2]);
                res[3] = fmaf(wgt, hif(v4.y), res[3]);
                res[4] = fmaf(wgt, lof(v4.z), res[4]);
                res[5] = fmaf(wgt, hif(v4.z), res[5]);
                res[6] = fmaf(wgt, lof(v4.w), res[6]);
                res[7] = fmaf(wgt, hif(v4.w), res[7]);
            }
        }
    }
    uint4 o4;
    o4.x = (unsigned)f2b(res[0]) | ((unsigned)f2b(res[1]) << 16);
    o4.y = (unsigned)f2b(res[2]) | ((unsigned)f2b(res[3]) << 16);
    o4.z = (unsigned)f2b(res[4]) | ((unsigned)f2b(res[5]) << 16);
    o4.w = (unsigned)f2b(res[6]) | ((unsigned)f2b(res[7]) << 16);
    *(uint4*)(Bt + (size_t)p*KK_ + k*64 + g*CPG_) = o4;
}

// ---------------------------------------------------------------------------
// 128x128 MFMA GEMM (m97 structure): M=768, N=P_, K=1728, BK=32.
// Wave w stages A/B chunks {2w,2w+1}; computes quadrant (mh=w>>1, nh=w&1)
// 4x4 of 16x16 tiles -> 16 MFMA + 8 ds_read_b128 per K-step.
// bid swizzle: 48-block chunks = 8 ntiles x 6 mtiles for per-XCD B reuse.
// ---------------------------------------------------------------------------
__global__ __launch_bounds__(256) void gemm128_kernel(
    const unsigned short* __restrict__ A,    // [768][1728] bf16
    const unsigned short* __restrict__ Bt,   // [P_][1728] bf16
    const float* __restrict__ bias,          // [648]
    unsigned short* __restrict__ out)        // out[co*P_ + col], co < 648
{
    __shared__ __align__(16) short As[8*512];
    __shared__ __align__(16) short Bs[8*512];
    int w = threadIdx.x >> 6, lane = threadIdx.x & 63;
    int bid = blockIdx.x, mt, nt;
    if (bid < 1152) { int c = bid/48, r = bid%48; mt = r >> 3; nt = c*8 + (r&7); }
    else            { int r = bid - 1152;         mt = r >> 2; nt = 192 + (r&3); }
    int m0 = mt*128, p0 = nt*128;
    int lm = lane & 15, lq = lane >> 4;

    const char* Ab = (const char*)A  + (size_t)(m0 + w*32 + lm)*KB_ + lq*16;
    const char* Bb = (const char*)Bt + (size_t)(p0 + w*32 + lm)*KB_ + lq*16;

    auto ldsA0 = (AS3 unsigned*)(As + (2*w)*512);
    auto ldsA1 = (AS3 unsigned*)(As + (2*w+1)*512);
    auto ldsB0 = (AS3 unsigned*)(Bs + (2*w)*512);
    auto ldsB1 = (AS3 unsigned*)(Bs + (2*w+1)*512);

    int mh = w >> 1, nh = w & 1;
    floatx4 acc[4][4];
    #pragma unroll
    for (int i = 0; i < 4; ++i)
        #pragma unroll
        for (int j = 0; j < 4; ++j)
            acc[i][j] = (floatx4){0.f, 0.f, 0.f, 0.f};

    for (int kt = 0; kt < 54; ++kt) {
        __syncthreads();
        __builtin_amdgcn_global_load_lds((const AS1 unsigned*)(Ab + kt*64),              ldsA0, 16, 0, 0);
        __builtin_amdgcn_global_load_lds((const AS1 unsigned*)(Ab + 16*KB_ + kt*64),     ldsA1, 16, 0, 0);
        __builtin_amdgcn_global_load_lds((const AS1 unsigned*)(Bb + kt*64),              ldsB0, 16, 0, 0);
        __builtin_amdgcn_global_load_lds((const AS1 unsigned*)(Bb + 16*KB_ + kt*64),     ldsB1, 16, 0, 0);
        __syncthreads();
        shortx8 a[4], b[4];
        #pragma unroll
        for (int i = 0; i < 4; ++i) a[i] = *(const shortx8*)&As[(4*mh+i)*512 + lane*8];
        #pragma unroll
        for (int j = 0; j < 4; ++j) b[j] = *(const shortx8*)&Bs[(4*nh+j)*512 + lane*8];
        #pragma unroll
        for (int i = 0; i < 4; ++i)
            #pragma unroll
            for (int j = 0; j < 4; ++j)
                acc[i][j] = __builtin_amdgcn_mfma_f32_16x16x32_bf16(a[i], b[j], acc[i][j], 0, 0, 0);
    }

    #pragma unroll
    for (int i = 0; i < 4; ++i) {
        int cob = m0 + (4*mh+i)*16 + lq*4;
        #pragma unroll
        for (int r = 0; r < 4; ++r) {
            int co = cob + r;
            if (co < CO_OFF_) {
                float bv = bias[co];
                #pragma unroll
                for (int j = 0; j < 4; ++j) {
                    int col = p0 + (4*nh+j)*16 + lm;
                    out[(size_t)co*P_ + col] = f2b(acc[i][j][r] + bv);
                }
            }
        }
    }
}

// ---------------------------------------------------------------------------
// 64x64 MFMA GEMM, BK=64: M=64, N=P_, K=1728 in 27 steps.
// Wave w stages A/B chunks {w, w+4} (ksub 0/1); computes 2x2 of 16x16 tiles
// per ksub -> 8 MFMA + 8 ds_read_b128 per K-step. Grid = 392 blocks.
// ---------------------------------------------------------------------------
__global__ __launch_bounds__(256) void gemm64_kernel(
    const unsigned short* __restrict__ A,    // [64][1728] bf16
    const unsigned short* __restrict__ Bt,   // [P_][1728] bf16
    const float* __restrict__ bias,          // [64] or nullptr
    unsigned short* __restrict__ out)        // out[co*P_ + col]
{
    __shared__ __align__(16) short As[8*512];
    __shared__ __align__(16) short Bs[8*512];
    int w = threadIdx.x >> 6, lane = threadIdx.x & 63;
    int p0 = blockIdx.x*64;
    int lm = lane & 15, lq = lane >> 4;

    const char* Ab = (const char*)A  + (size_t)(w*16 + lm)*KB_ + lq*16;
    const char* Bb = (const char*)Bt + (size_t)(p0 + w*16 + lm)*KB_ + lq*16;

    auto ldsA0 = (AS3 unsigned*)(As + w*512);
    auto ldsA1 = (AS3 unsigned*)(As + (4+w)*512);
    auto ldsB0 = (AS3 unsigned*)(Bs + w*512);
    auto ldsB1 = (AS3 unsigned*)(Bs + (4+w)*512);

    int mh = w >> 1, nh = w & 1;
    floatx4 acc[2][2];
    #pragma unroll
    for (int i = 0; i < 2; ++i)
        #pragma unroll
        for (int j = 0; j < 2; ++j)
            acc[i][j] = (floatx4){0.f, 0.f, 0.f, 0.f};

    for (int kt = 0; kt < 27; ++kt) {
        __syncthreads();
        __builtin_amdgcn_global_load_lds((const AS1 unsigned*)(Ab + kt*128),      ldsA0, 16, 0, 0);
        __builtin_amdgcn_global_load_lds((const AS1 unsigned*)(Ab + kt*128 + 64), ldsA1, 16, 0, 0);
        __builtin_amdgcn_global_load_lds((const AS1 unsigned*)(Bb + kt*128),      ldsB0, 16, 0, 0);
        __builtin_amdgcn_global_load_lds((const AS1 unsigned*)(Bb + kt*128 + 64), ldsB1, 16, 0, 0);
        __syncthreads();
        #pragma unroll
        for (int ks = 0; ks < 2; ++ks) {
            shortx8 a[2], b[2];
            #pragma unroll
            for (int i = 0; i < 2; ++i) a[i] = *(const shortx8*)&As[(ks*4 + 2*mh+i)*512 + lane*8];
            #pragma unroll
            for (int j = 0; j < 2; ++j) b[j] = *(const shortx8*)&Bs[(ks*4 + 2*nh+j)*512 + lane*8];
            #pragma unroll
            for (int i = 0; i < 2; ++i)
                #pragma unroll
                for (int j = 0; j < 2; ++j)
                    acc[i][j] = __builtin_amdgcn_mfma_f32_16x16x32_bf16(a[i], b[j], acc[i][j], 0, 0, 0);
        }
    }

    #pragma unroll
    for (int i = 0; i < 2; ++i) {
        int cob = (2*mh+i)*16 + lq*4;
        #pragma unroll
        for (int r = 0; r < 4; ++r) {
            int co = cob + r;
            float bv = bias ? bias[co] : 0.f;
            #pragma unroll
            for (int j = 0; j < 2; ++j) {
                int col = p0 + (2*nh+j)*16 + lm;
                out[(size_t)co*P_ + col] = f2b(acc[i][j][r] + bv);
            }
        }
    }
}

// ---------------------------------------------------------------------------
__global__ __launch_bounds__(256) void bn_stats_kernel(
    const unsigned short* __restrict__ src, float* __restrict__ stats)
{
    int c   = blockIdx.x;
    int tid = threadIdx.x;
    float s = 0.f, q = 0.f;
    for (int n = 0; n < N_; ++n) {
        const unsigned short* p = src + ((size_t)n*C_ + c)*P_;
        for (int i = tid; i < P_; i += 256) {
            float v = b2f(p[i]);
            s += v;
            q = fmaf(v, v, q);
        }
    }
    #pragma unroll
    for (int o = 32; o; o >>= 1) {
        s += __shfl_down(s, o);
        q += __shfl_down(q, o);
    }
    __shared__ float sh[2][4];
    int wave = tid >> 6;
    if ((tid & 63) == 0) { sh[0][wave] = s; sh[1][wave] = q; }
    __syncthreads();
    if (tid == 0) {
        float S = sh[0][0] + sh[0][1] + sh[0][2] + sh[0][3];
        float Q = sh[1][0] + sh[1][1] + sh[1][2] + sh[1][3];
        const float inv = 1.f / (float)(N_*P_);
        float m  = S * inv;
        float var = Q * inv - m*m;
        stats[c]      = m;
        stats[C_ + c] = rsqrtf(var + 1e-5f);
    }
}

// out = relu(gamma*(y2-mean)*rstd + beta + x)   fp32 out
__global__ __launch_bounds__(256) void bn_add_relu_kernel(
    const unsigned short* __restrict__ y2, const float* __restrict__ x,
    const float* __restrict__ stats,
    const float* __restrict__ gamma, const float* __restrict__ beta,
    float* __restrict__ out)
{
    size_t idx = (size_t)blockIdx.x*256 + threadIdx.x;
    int c = (int)((idx / P_) % C_);
    float v = (b2f(y2[idx]) - stats[c]) * stats[C_ + c] * gamma[c] + beta[c] + x[idx];
    out[idx] = fmaxf(v, 0.f);
}

// ---------------------------------------------------------------------------
extern "C" void kernel_launch(void* const* d_in, const int* in_sizes, int n_in,
                              void* d_out, int out_size, void* d_ws, size_t ws_size,
                              hipStream_t stream) {
    const float* x     = (const float*)d_in[0];
    const float* w_off = (const float*)d_in[1];
    const float* b_off = (const float*)d_in[2];
    const float* w1    = (const float*)d_in[3];
    const float* g1    = (const float*)d_in[4];
    const float* be1   = (const float*)d_in[5];
    const float* w2    = (const float*)d_in[6];
    const float* b2    = (const float*)d_in[7];
    const float* g2    = (const float*)d_in[8];
    const float* be2   = (const float*)d_in[9];
    float* out = (float*)d_out;

    // workspace (~148 MB; 149 MB proven safe in Round 1)
    float* st1 = (float*)d_ws;                               // 128
    float* st2 = st1 + 128;                                  // 128
    unsigned short* Bt  = (unsigned short*)(st2 + 128);      // P_*1728 (86.7 MB, reused)
    unsigned short* off = Bt  + (size_t)P_*KK_;              // 648*P bf16 (32.5 MB, per-n)
    unsigned short* xb  = off + (size_t)CO_OFF_*P_;          // N*64*P bf16 (6.4 MB)
    unsigned short* xt  = xb  + (size_t)N_*C_*P_;            // N*P*64 bf16 (6.4 MB)
    unsigned short* y1  = xt  + (size_t)N_*C_*P_;            // N*64*P bf16 (6.4 MB)
    unsigned short* y2  = y1  + (size_t)N_*C_*P_;            // N*64*P bf16 (6.4 MB)
    unsigned short* A1  = y2  + (size_t)N_*C_*P_;            // 768*1728 bf16 (2.65 MB)
    unsigned short* A2  = A1  + (size_t)MP_*KK_;             // 64*1728 bf16
    unsigned short* A1t = A2  + (size_t)C_*KK_;              // 64*1728 bf16

    // prep
    cast_f2b_kernel<<<(N_*C_*P_+255)/256, 256, 0, stream>>>(x, xb, N_*C_*P_);
    transpose_xt_kernel<<<N_*(P_/64), 256, 0, stream>>>(xb, xt);
    pad_w_kernel<<<(MP_*KK_+255)/256, 256, 0, stream>>>(w_off, A1);
    cast_f2b_kernel<<<(C_*KK_+255)/256, 256, 0, stream>>>(w2, A2, C_*KK_);
    perm_w1_kernel<<<(C_*KK_+255)/256, 256, 0, stream>>>(w1, A1t);

    // per-n: conv_off (im2col + 128-tile GEMM) then deform (gather + 64-tile GEMM)
    for (int n = 0; n < N_; ++n) {
        im2col_kernel<<<P_/4, 256, 0, stream>>>(xb + (size_t)n*C_*P_, Bt);
        gemm128_kernel<<<1176, 256, 0, stream>>>(A1, Bt, b_off, off);
        gather_kernel<<<216*(P_/256), 256, 0, stream>>>(xt, off, Bt, n);
        gemm64_kernel<<<P_/64, 256, 0, stream>>>(A1t, Bt, (const float*)nullptr,
            y1 + (size_t)n*C_*P_);
    }

    // BN1 stats (apply fused into conv2's im2col)
    bn_stats_kernel<<<C_, 256, 0, stream>>>(y1, st1);

    // conv2: im2col(+BN1+ReLU) + 64-tile GEMM -> y2 bf16
    for (int n = 0; n < N_; ++n) {
        im2col_bn_kernel<<<P_/4, 256, 0, stream>>>(y1 + (size_t)n*C_*P_, st1, g1, be1, Bt);
        gemm64_kernel<<<P_/64, 256, 0, stream>>>(A2, Bt, b2, y2 + (size_t)n*C_*P_);
    }

    // BN2 + residual + ReLU -> out (fp32)
    bn_stats_kernel<<<C_, 256, 0, stream>>>(y2, st2);
    bn_add_relu_kernel<<<(N_*C_*P_)/256, 256, 0, stream>>>(y2, x, st2, g2, be2, out);
}